// Round 8
// baseline (408.709 us; speedup 1.0000x reference)
//
#include <hip/hip_runtime.h>

// GCN 3-layer: N=100000 nodes, E=1.6M edges, dims 128 -> 64 -> 64 -> 32.
// Round 8: agg is latency-bound (VALUBusy 40%, 1.9TB/s L2-fill vs compulsory
// 91MB cross-XCD H replication). Changes vs round 7:
//  (a) software-pipelined gather in agg: prefetch next 8-edge epack chunk
//      while current chunk's H gathers are in flight -> ~1 latency per 8
//      edges instead of 2.
//  (b) epack.x stores the byte offset (src<<7) of the bf16 H row for C=64
//      -> per-gather address = one 32-bit add onto a uniform base (saddr
//      global_load_ushort); C=32 uses (x>>1).
// CSR build (LDS bucket sort, no per-edge global atomics) and GEMMs unchanged.
// ws: dinv | rowptr | degi | bcur | bsum | boff | bbuf | epack | P(bf16) | Q(f32)

#define BLK 256
#define SCAN_CHUNK 1024   // nodes per scan block (256 threads x 4)
#define BSHIFT 8          // 256 nodes per bucket
#define BMASK 255
#define BCAP 6144         // slots per bucket; E[size]=4092, sigma~64
#define BCH 4096          // edges per bucket_kernel block

__device__ __forceinline__ float bf2f(unsigned short u) {
    return __uint_as_float(((unsigned int)u) << 16);
}
__device__ __forceinline__ unsigned short f2bf(float f) {
    unsigned int x = __float_as_uint(f);
    unsigned int r = (x + 0x7FFFu + ((x >> 16) & 1u)) >> 16;   // RNE
    return (unsigned short)r;
}

// Phase 1: bucketize edges by dst>>8. Per-edge atomics are LDS-only; global
// atomics = one reservation per (block,bucket) with nonzero count.
__global__ __launch_bounds__(256) void bucket_kernel(const int* __restrict__ src,
                                                     const int* __restrict__ dst,
                                                     int* __restrict__ bcur,
                                                     unsigned int* __restrict__ bbuf,
                                                     int E, int NB) {
    __shared__ int hist[512];
    __shared__ int base_[512];
    const int tid = threadIdx.x;
    const int e0 = blockIdx.x * BCH;
    const int e1 = min(e0 + BCH, E);
    for (int i = tid; i < NB; i += 256) hist[i] = 0;
    __syncthreads();
    for (int e = e0 + tid; e < e1; e += 256)
        atomicAdd(&hist[dst[e] >> BSHIFT], 1);                 // LDS atomic
    __syncthreads();
    for (int i = tid; i < NB; i += 256) {
        int c = hist[i];
        base_[i] = c ? atomicAdd(&bcur[i], c) : 0;             // global, 1/bucket
        hist[i] = 0;                                           // reuse as cursor
    }
    __syncthreads();
    for (int e = e0 + tid; e < e1; e += 256) {
        int d = dst[e];
        int b = d >> BSHIFT;
        int idx = base_[b] + atomicAdd(&hist[b], 1);           // LDS atomic
        if (idx < BCAP)
            bbuf[(size_t)b * BCAP + idx] =
                ((unsigned int)src[e] << BSHIFT) | (unsigned int)(d & BMASK);
    }
}

// Phase 2a: per-bucket degree histogram -> plain stores (no global atomics).
__global__ __launch_bounds__(256) void bdeg_kernel(const int* __restrict__ bcur,
                                                   const unsigned int* __restrict__ bbuf,
                                                   int* __restrict__ degi, int N) {
    __shared__ int hist[256];
    const int b = blockIdx.x;
    const int tid = threadIdx.x;
    hist[tid] = 0;
    __syncthreads();
    const int cnt = min(bcur[b], BCAP);
    const unsigned int* p = bbuf + (size_t)b * BCAP;
    for (int i = tid; i < cnt; i += 256)
        atomicAdd(&hist[p[i] & BMASK], 1);                     // LDS atomic
    __syncthreads();
    const int node = (b << BSHIFT) + tid;
    if (node < N) degi[node] = hist[tid];
}

__global__ void dinv_kernel(const int* __restrict__ degi, float* __restrict__ dinv, int N) {
    int i = blockIdx.x * blockDim.x + threadIdx.x;
    if (i < N) dinv[i] = rsqrtf((float)degi[i] + 1.0f);
}

// --- hierarchical scan: A) per-block reduce, B) scan block sums, C) local scan+offset ---
__global__ __launch_bounds__(256) void scanA_kernel(const int* __restrict__ degi,
                                                    int* __restrict__ bsum, int N) {
    const int t = threadIdx.x;
    const int base = blockIdx.x * SCAN_CHUNK + t * 4;
    int s = 0;
#pragma unroll
    for (int j = 0; j < 4; ++j) { int i = base + j; if (i < N) s += degi[i]; }
    __shared__ int red[256];
    red[t] = s;
    __syncthreads();
    for (int off = 128; off > 0; off >>= 1) {
        if (t < off) red[t] += red[t + off];
        __syncthreads();
    }
    if (t == 0) bsum[blockIdx.x] = red[0];
}

// NBLK <= 256. Exclusive scan of bsum -> boff; total -> rowptr[N].
__global__ __launch_bounds__(256) void scanB_kernel(const int* __restrict__ bsum,
                                                    int* __restrict__ boff,
                                                    int* __restrict__ rowptr_last, int NBLK) {
    __shared__ int sh[256];
    const int t = threadIdx.x;
    sh[t] = (t < NBLK) ? bsum[t] : 0;
    __syncthreads();
    for (int off = 1; off < 256; off <<= 1) {
        int u = (t >= off) ? sh[t - off] : 0;
        __syncthreads();
        sh[t] += u;
        __syncthreads();
    }
    if (t < NBLK) boff[t] = (t == 0) ? 0 : sh[t - 1];
    if (t == 0) *rowptr_last = sh[255];
}

__global__ __launch_bounds__(256) void scanC_kernel(const int* __restrict__ degi,
                                                    const int* __restrict__ boff,
                                                    int* __restrict__ rowptr, int N) {
    const int t = threadIdx.x;
    const int base = blockIdx.x * SCAN_CHUNK + t * 4;
    int loc[4];
    int s = 0;
#pragma unroll
    for (int j = 0; j < 4; ++j) {
        int i = base + j;
        loc[j] = (i < N) ? degi[i] : 0;
        s += loc[j];
    }
    __shared__ int sh[256];
    sh[t] = s;
    __syncthreads();
    for (int off = 1; off < 256; off <<= 1) {
        int u = (t >= off) ? sh[t - off] : 0;
        __syncthreads();
        sh[t] += u;
        __syncthreads();
    }
    int ex = ((t == 0) ? 0 : sh[t - 1]) + boff[blockIdx.x];
#pragma unroll
    for (int j = 0; j < 4; ++j) {
        int i = base + j;
        if (i < N) { rowptr[i] = ex; ex += loc[j]; }
    }
}

// Phase 2b: per-bucket CSR fill. LDS cursors seeded from rowptr; per-edge
// atomics are LDS-only. epack.x = byte offset of bf16 H row (src<<7, C=64).
__global__ __launch_bounds__(256) void bfill_kernel(const int* __restrict__ bcur,
                                                    const unsigned int* __restrict__ bbuf,
                                                    const int* __restrict__ rowptr,
                                                    const float* __restrict__ dinv,
                                                    int2* __restrict__ epack, int N) {
    __shared__ int cur[256];
    __shared__ float sdinv[256];
    const int b = blockIdx.x;
    const int tid = threadIdx.x;
    const int node = (b << BSHIFT) + tid;
    cur[tid] = (node < N) ? rowptr[node] : 0;
    sdinv[tid] = (node < N) ? dinv[node] : 0.f;
    __syncthreads();
    const int cnt = min(bcur[b], BCAP);
    const unsigned int* p = bbuf + (size_t)b * BCAP;
    for (int i = tid; i < cnt; i += 256) {
        unsigned int v = p[i];
        int s = (int)(v >> BSHIFT);
        int dl = (int)(v & BMASK);
        int slot = atomicAdd(&cur[dl], 1);                     // LDS atomic
        epack[slot] = make_int2(s << 7, __float_as_int(dinv[s] * sdinv[dl]));
    }
}

// Y[N,C](bf16) = X[N,K](f32) @ W[K,C](f32).
template<int K, int C, int RT>
__global__ __launch_bounds__(256) void gemm_kernel(const float* __restrict__ X,
                                                   const float* __restrict__ W,
                                                   unsigned short* __restrict__ Y, int N) {
    constexpr int CG = C / 4;        // col groups (threads per row-group)
    constexpr int RG = 256 / CG;     // row groups
    constexpr int ROWS = RG * RT;    // rows per block
    __shared__ float Wl[K * C];
    __shared__ float Xl[ROWS * (K + 1)];
    const int tid = threadIdx.x;

    for (int i = tid; i < K * C / 4; i += 256)
        ((float4*)Wl)[i] = ((const float4*)W)[i];

    const int row0 = blockIdx.x * ROWS;
    for (int idx = tid; idx < ROWS * (K / 4); idx += 256) {
        int r = idx / (K / 4), kc = idx % (K / 4);
        float4 v = make_float4(0.f, 0.f, 0.f, 0.f);
        int gr = row0 + r;
        if (gr < N) v = ((const float4*)X)[(size_t)gr * (K / 4) + kc];
        float* p = &Xl[r * (K + 1) + kc * 4];
        p[0] = v.x; p[1] = v.y; p[2] = v.z; p[3] = v.w;
    }
    __syncthreads();

    const int cg = tid % CG, rg = tid / CG;
    float acc[RT][4];
#pragma unroll
    for (int j = 0; j < RT; ++j)
#pragma unroll
        for (int c = 0; c < 4; ++c) acc[j][c] = 0.f;

#pragma unroll 4
    for (int k = 0; k < K; ++k) {
        float4 w = *(const float4*)&Wl[k * C + cg * 4];
#pragma unroll
        for (int j = 0; j < RT; ++j) {
            float xv = Xl[(rg * RT + j) * (K + 1) + k];
            acc[j][0] += xv * w.x;
            acc[j][1] += xv * w.y;
            acc[j][2] += xv * w.z;
            acc[j][3] += xv * w.w;
        }
    }

#pragma unroll
    for (int j = 0; j < RT; ++j) {
        int gr = row0 + rg * RT + j;
        if (gr < N) {
            ushort4 o;
            o.x = f2bf(acc[j][0]); o.y = f2bf(acc[j][1]);
            o.z = f2bf(acc[j][2]); o.w = f2bf(acc[j][3]);
            *(ushort4*)&Y[(size_t)gr * C + cg * 4] = o;
        }
    }
}

// Per-edge H gather: epack.x is the byte offset for C=64 rows; C=32 shifts.
template<int C>
__device__ __forceinline__ float gath(const char* __restrict__ Hb, int ex, int foff) {
    unsigned o = (C == 64) ? (unsigned)ex : ((unsigned)ex >> 1);
    return bf2f(*(const unsigned short*)(Hb + o + foff));
}

// CSR gather aggregation over bf16 H, software-pipelined (prefetch next 8
// epack while current 8 H gathers are in flight). f32 out, fused bias/relu.
template<int C, bool RELU>
__global__ __launch_bounds__(256) void agg_kernel(const unsigned short* __restrict__ H,
                                                  const int* __restrict__ rowptr,
                                                  const int2* __restrict__ epack,
                                                  const float* __restrict__ dinv,
                                                  const float* __restrict__ bias,
                                                  float* __restrict__ OUT, int N) {
    constexpr int NPB = 256 / C;
    const int f = threadIdx.x % C;                       // feature lane
    const int node = blockIdx.x * NPB + threadIdx.x / C;
    if (node >= N) return;
    const int lo = rowptr[node], hi = rowptr[node + 1];
    const float di = dinv[node];
    const char* Hb = (const char*)H;
    const int foff = f * 2;

    float a0 = 0.f, a1 = 0.f, a2 = 0.f, a3 = 0.f;
    int i = lo;
    if (i + 8 <= hi) {
        int2 e0 = epack[i + 0], e1 = epack[i + 1], e2 = epack[i + 2], e3 = epack[i + 3];
        int2 e4 = epack[i + 4], e5 = epack[i + 5], e6 = epack[i + 6], e7 = epack[i + 7];
        for (;;) {
            const int inext = i + 8;
            const bool more = (inext + 8 <= hi);
            int2 n0, n1, n2, n3, n4, n5, n6, n7;
            if (more) {                                  // prefetch next chunk
                n0 = epack[inext + 0]; n1 = epack[inext + 1];
                n2 = epack[inext + 2]; n3 = epack[inext + 3];
                n4 = epack[inext + 4]; n5 = epack[inext + 5];
                n6 = epack[inext + 6]; n7 = epack[inext + 7];
            }
            float h0 = gath<C>(Hb, e0.x, foff);
            float h1 = gath<C>(Hb, e1.x, foff);
            float h2 = gath<C>(Hb, e2.x, foff);
            float h3 = gath<C>(Hb, e3.x, foff);
            float h4 = gath<C>(Hb, e4.x, foff);
            float h5 = gath<C>(Hb, e5.x, foff);
            float h6 = gath<C>(Hb, e6.x, foff);
            float h7 = gath<C>(Hb, e7.x, foff);
            a0 = fmaf(h0, __int_as_float(e0.y), a0);
            a1 = fmaf(h1, __int_as_float(e1.y), a1);
            a2 = fmaf(h2, __int_as_float(e2.y), a2);
            a3 = fmaf(h3, __int_as_float(e3.y), a3);
            a0 = fmaf(h4, __int_as_float(e4.y), a0);
            a1 = fmaf(h5, __int_as_float(e5.y), a1);
            a2 = fmaf(h6, __int_as_float(e6.y), a2);
            a3 = fmaf(h7, __int_as_float(e7.y), a3);
            i = inext;
            if (!more) break;
            e0 = n0; e1 = n1; e2 = n2; e3 = n3;
            e4 = n4; e5 = n5; e6 = n6; e7 = n7;
        }
    }
    for (; i + 4 <= hi; i += 4) {
        int2 e0 = epack[i + 0], e1 = epack[i + 1], e2 = epack[i + 2], e3 = epack[i + 3];
        float h0 = gath<C>(Hb, e0.x, foff);
        float h1 = gath<C>(Hb, e1.x, foff);
        float h2 = gath<C>(Hb, e2.x, foff);
        float h3 = gath<C>(Hb, e3.x, foff);
        a0 = fmaf(h0, __int_as_float(e0.y), a0);
        a1 = fmaf(h1, __int_as_float(e1.y), a1);
        a2 = fmaf(h2, __int_as_float(e2.y), a2);
        a3 = fmaf(h3, __int_as_float(e3.y), a3);
    }
    for (; i < hi; ++i) {
        int2 e0 = epack[i];
        a0 = fmaf(gath<C>(Hb, e0.x, foff), __int_as_float(e0.y), a0);
    }

    float r = (a0 + a1) + (a2 + a3)
            + di * di * bf2f(H[(size_t)node * C + f])
            + bias[f];
    if (RELU) r = fmaxf(r, 0.f);
    OUT[(size_t)node * C + f] = r;
}

extern "C" void kernel_launch(void* const* d_in, const int* in_sizes, int n_in,
                              void* d_out, int out_size, void* d_ws, size_t ws_size,
                              hipStream_t stream) {
    const float* x  = (const float*)d_in[0];
    const int*   ei = (const int*)d_in[1];
    const float* W1 = (const float*)d_in[2];
    const float* b1 = (const float*)d_in[3];
    const float* W2 = (const float*)d_in[4];
    const float* b2 = (const float*)d_in[5];
    const float* W3 = (const float*)d_in[6];
    const float* b3 = (const float*)d_in[7];
    float* out = (float*)d_out;

    const int N = in_sizes[0] / 128;
    const int E = in_sizes[1] / 2;
    const int* src = ei;
    const int* dst = ei + E;
    const int NSCAN = (N + SCAN_CHUNK - 1) / SCAN_CHUNK;        // 98
    const int NB = (N + BMASK) >> BSHIFT;                        // 391 buckets
    const int NBB = (E + BCH - 1) / BCH;                         // 391 blocks

    auto align = [](size_t v) { return (v + 255) & ~(size_t)255; };
    char* wsb = (char*)d_ws;
    size_t off = 0;
    float* dinv   = (float*)(wsb + off); off += align((size_t)N * 4);
    int*   rowptr = (int*)  (wsb + off); off += align((size_t)(N + 1) * 4);
    int*   degi   = (int*)  (wsb + off); off += align((size_t)N * 4);
    int*   bcur   = (int*)  (wsb + off); off += align((size_t)NB * 4);
    int*   bsum   = (int*)  (wsb + off); off += align((size_t)NSCAN * 4);
    int*   boff   = (int*)  (wsb + off); off += align((size_t)NSCAN * 4);
    unsigned int* bbuf = (unsigned int*)(wsb + off); off += align((size_t)NB * BCAP * 4);
    int2*  epack  = (int2*) (wsb + off); off += align((size_t)E * 8);
    unsigned short* P = (unsigned short*)(wsb + off); off += align((size_t)N * 64 * 2);
    float* Q      = (float*)(wsb + off);

    // ---- CSR build (no per-edge global atomics) ----
    hipMemsetAsync(bcur, 0, (size_t)NB * 4, stream);
    bucket_kernel<<<NBB, 256, 0, stream>>>(src, dst, bcur, bbuf, E, NB);
    bdeg_kernel<<<NB, 256, 0, stream>>>(bcur, bbuf, degi, N);
    dinv_kernel<<<(N + BLK - 1) / BLK, BLK, 0, stream>>>(degi, dinv, N);
    scanA_kernel<<<NSCAN, 256, 0, stream>>>(degi, bsum, N);
    scanB_kernel<<<1, 256, 0, stream>>>(bsum, boff, rowptr + N, NSCAN);
    scanC_kernel<<<NSCAN, 256, 0, stream>>>(degi, boff, rowptr, N);
    bfill_kernel<<<NB, 256, 0, stream>>>(bcur, bbuf, rowptr, dinv, epack, N);

    // ---- Layer 1: 128 -> 64, relu ----
    gemm_kernel<128, 64, 2><<<(N + 31) / 32, BLK, 0, stream>>>(x, W1, P, N);
    agg_kernel<64, true><<<(N * 64 + BLK - 1) / BLK, BLK, 0, stream>>>(P, rowptr, epack,
                                                                       dinv, b1, Q, N);

    // ---- Layer 2: 64 -> 64, relu ----
    gemm_kernel<64, 64, 4><<<(N + 63) / 64, BLK, 0, stream>>>(Q, W2, P, N);
    agg_kernel<64, true><<<(N * 64 + BLK - 1) / BLK, BLK, 0, stream>>>(P, rowptr, epack,
                                                                       dinv, b2, Q, N);

    // ---- Layer 3: 64 -> 32, no relu, write d_out ----
    gemm_kernel<64, 32, 4><<<(N + 127) / 128, BLK, 0, stream>>>(Q, W3, P, N);
    agg_kernel<32, false><<<(N * 32 + BLK - 1) / BLK, BLK, 0, stream>>>(P, rowptr, epack,
                                                                        dinv, b3, out, N);
}

// Round 9
// 355.562 us; speedup vs baseline: 1.1495x; 1.1495x over previous
//
#include <hip/hip_runtime.h>

// GCN 3-layer: N=100000 nodes, E=1.6M edges, dims 128 -> 64 -> 64 -> 32.
// Round 9:
//  (a) REVERT round-8's software-pipelined agg (VGPR 28->40, occ 68->52%,
//      61->72us: prefetch sat between gathers and consumers in vmcnt order).
//      Back to round-7 8-unrolled loop + byte-offset epack.
//  (b) GEMMs -> bf16 MFMA (v_mfma_f32_16x16x32_bf16), register A-frags,
//      B-frags from pre-transposed bf16 Wt in ws (wcvt prep kernel), no LDS.
//      A: lane(row=l&15, k=(l>>4)*8+j); B: lane(col=l&15, k=(l>>4)*8+j);
//      C/D: col=l&15, row=(l>>4)*4+i (m89-verified mapping).
//  (c) agg<64> writes bf16 Q (gemm2/3 A-input), final agg<32> writes f32 out.
//  (d) dinv fused into bdeg.
// ws: dinv | rowptr | degi | bcur | bsum | boff | bbuf | epack | P | Q | Wt1-3

#define BLK 256
#define SCAN_CHUNK 1024   // nodes per scan block (256 threads x 4)
#define BSHIFT 8          // 256 nodes per bucket
#define BMASK 255
#define BCAP 6144         // slots per bucket; E[size]=4092, sigma~64
#define BCH 4096          // edges per bucket_kernel block

typedef __attribute__((ext_vector_type(8))) short short8v;
typedef __attribute__((ext_vector_type(4))) float f32x4;

__device__ __forceinline__ float bf2f(unsigned short u) {
    return __uint_as_float(((unsigned int)u) << 16);
}
__device__ __forceinline__ unsigned short f2bf(float f) {
    unsigned int x = __float_as_uint(f);
    unsigned int r = (x + 0x7FFFu + ((x >> 16) & 1u)) >> 16;   // RNE
    return (unsigned short)r;
}

// Phase 1: bucketize edges by dst>>8. Per-edge atomics are LDS-only; global
// atomics = one reservation per (block,bucket) with nonzero count.
__global__ __launch_bounds__(256) void bucket_kernel(const int* __restrict__ src,
                                                     const int* __restrict__ dst,
                                                     int* __restrict__ bcur,
                                                     unsigned int* __restrict__ bbuf,
                                                     int E, int NB) {
    __shared__ int hist[512];
    __shared__ int base_[512];
    const int tid = threadIdx.x;
    const int e0 = blockIdx.x * BCH;
    const int e1 = min(e0 + BCH, E);
    for (int i = tid; i < NB; i += 256) hist[i] = 0;
    __syncthreads();
    for (int e = e0 + tid; e < e1; e += 256)
        atomicAdd(&hist[dst[e] >> BSHIFT], 1);                 // LDS atomic
    __syncthreads();
    for (int i = tid; i < NB; i += 256) {
        int c = hist[i];
        base_[i] = c ? atomicAdd(&bcur[i], c) : 0;             // global, 1/bucket
        hist[i] = 0;                                           // reuse as cursor
    }
    __syncthreads();
    for (int e = e0 + tid; e < e1; e += 256) {
        int d = dst[e];
        int b = d >> BSHIFT;
        int idx = base_[b] + atomicAdd(&hist[b], 1);           // LDS atomic
        if (idx < BCAP)
            bbuf[(size_t)b * BCAP + idx] =
                ((unsigned int)src[e] << BSHIFT) | (unsigned int)(d & BMASK);
    }
}

// Phase 2a: per-bucket degree histogram -> plain degi/dinv stores (fused).
__global__ __launch_bounds__(256) void bdeg_kernel(const int* __restrict__ bcur,
                                                   const unsigned int* __restrict__ bbuf,
                                                   int* __restrict__ degi,
                                                   float* __restrict__ dinv, int N) {
    __shared__ int hist[256];
    const int b = blockIdx.x;
    const int tid = threadIdx.x;
    hist[tid] = 0;
    __syncthreads();
    const int cnt = min(bcur[b], BCAP);
    const unsigned int* p = bbuf + (size_t)b * BCAP;
    for (int i = tid; i < cnt; i += 256)
        atomicAdd(&hist[p[i] & BMASK], 1);                     // LDS atomic
    __syncthreads();
    const int node = (b << BSHIFT) + tid;
    if (node < N) {
        int dg = hist[tid];
        degi[node] = dg;
        dinv[node] = rsqrtf((float)dg + 1.0f);
    }
}

// --- hierarchical scan: A) per-block reduce, B) scan block sums, C) local scan+offset ---
__global__ __launch_bounds__(256) void scanA_kernel(const int* __restrict__ degi,
                                                    int* __restrict__ bsum, int N) {
    const int t = threadIdx.x;
    const int base = blockIdx.x * SCAN_CHUNK + t * 4;
    int s = 0;
#pragma unroll
    for (int j = 0; j < 4; ++j) { int i = base + j; if (i < N) s += degi[i]; }
    __shared__ int red[256];
    red[t] = s;
    __syncthreads();
    for (int off = 128; off > 0; off >>= 1) {
        if (t < off) red[t] += red[t + off];
        __syncthreads();
    }
    if (t == 0) bsum[blockIdx.x] = red[0];
}

// NBLK <= 256. Exclusive scan of bsum -> boff; total -> rowptr[N].
__global__ __launch_bounds__(256) void scanB_kernel(const int* __restrict__ bsum,
                                                    int* __restrict__ boff,
                                                    int* __restrict__ rowptr_last, int NBLK) {
    __shared__ int sh[256];
    const int t = threadIdx.x;
    sh[t] = (t < NBLK) ? bsum[t] : 0;
    __syncthreads();
    for (int off = 1; off < 256; off <<= 1) {
        int u = (t >= off) ? sh[t - off] : 0;
        __syncthreads();
        sh[t] += u;
        __syncthreads();
    }
    if (t < NBLK) boff[t] = (t == 0) ? 0 : sh[t - 1];
    if (t == 0) *rowptr_last = sh[255];
}

__global__ __launch_bounds__(256) void scanC_kernel(const int* __restrict__ degi,
                                                    const int* __restrict__ boff,
                                                    int* __restrict__ rowptr, int N) {
    const int t = threadIdx.x;
    const int base = blockIdx.x * SCAN_CHUNK + t * 4;
    int loc[4];
    int s = 0;
#pragma unroll
    for (int j = 0; j < 4; ++j) {
        int i = base + j;
        loc[j] = (i < N) ? degi[i] : 0;
        s += loc[j];
    }
    __shared__ int sh[256];
    sh[t] = s;
    __syncthreads();
    for (int off = 1; off < 256; off <<= 1) {
        int u = (t >= off) ? sh[t - off] : 0;
        __syncthreads();
        sh[t] += u;
        __syncthreads();
    }
    int ex = ((t == 0) ? 0 : sh[t - 1]) + boff[blockIdx.x];
#pragma unroll
    for (int j = 0; j < 4; ++j) {
        int i = base + j;
        if (i < N) { rowptr[i] = ex; ex += loc[j]; }
    }
}

// Phase 2b: per-bucket CSR fill. LDS cursors seeded from rowptr; per-edge
// atomics are LDS-only. epack.x = byte offset of bf16 H row (src<<7, C=64).
__global__ __launch_bounds__(256) void bfill_kernel(const int* __restrict__ bcur,
                                                    const unsigned int* __restrict__ bbuf,
                                                    const int* __restrict__ rowptr,
                                                    const float* __restrict__ dinv,
                                                    int2* __restrict__ epack, int N) {
    __shared__ int cur[256];
    __shared__ float sdinv[256];
    const int b = blockIdx.x;
    const int tid = threadIdx.x;
    const int node = (b << BSHIFT) + tid;
    cur[tid] = (node < N) ? rowptr[node] : 0;
    sdinv[tid] = (node < N) ? dinv[node] : 0.f;
    __syncthreads();
    const int cnt = min(bcur[b], BCAP);
    const unsigned int* p = bbuf + (size_t)b * BCAP;
    for (int i = tid; i < cnt; i += 256) {
        unsigned int v = p[i];
        int s = (int)(v >> BSHIFT);
        int dl = (int)(v & BMASK);
        int slot = atomicAdd(&cur[dl], 1);                     // LDS atomic
        epack[slot] = make_int2(s << 7, __float_as_int(dinv[s] * sdinv[dl]));
    }
}

// Convert + transpose the three weight matrices to bf16 Wt[C][K].
__global__ __launch_bounds__(256) void wcvt_kernel(const float* __restrict__ W1,
                                                   const float* __restrict__ W2,
                                                   const float* __restrict__ W3,
                                                   unsigned short* __restrict__ Wt1,
                                                   unsigned short* __restrict__ Wt2,
                                                   unsigned short* __restrict__ Wt3) {
    int i = blockIdx.x * 256 + threadIdx.x;
    if (i < 8192) {                       // W1: 128x64
        int k = i >> 6, c = i & 63;
        Wt1[c * 128 + k] = f2bf(W1[i]);
    } else if (i < 12288) {               // W2: 64x64
        int j = i - 8192;
        int k = j >> 6, c = j & 63;
        Wt2[c * 64 + k] = f2bf(W2[j]);
    } else if (i < 14336) {               // W3: 64x32
        int j = i - 12288;
        int k = j >> 5, c = j & 31;
        Wt3[c * 64 + k] = f2bf(W3[j]);
    }
}

// Y[N,C](bf16) = X[N,K] @ Wt^T, via v_mfma_f32_16x16x32_bf16.
// Block = 4 waves, wave w owns rows blockIdx*64 + w*16 .. +15. No LDS.
// A-frag: lane(row=l&15, k=(l>>4)*8+j); B-frag from Wt[C][K] (K-contiguous);
// C/D: col=l&15, row=(l>>4)*4+i.
template<int K, int C, bool AF32>
__global__ __launch_bounds__(256) void gemm_mfma(const void* __restrict__ Xv,
                                                 const unsigned short* __restrict__ Wt,
                                                 unsigned short* __restrict__ Y, int N) {
    constexpr int NS = K / 32;            // k-steps
    constexpr int NT = C / 16;            // col-tiles
    const int lane = threadIdx.x & 63;
    const int wave = threadIdx.x >> 6;
    const int r0 = blockIdx.x * 64 + wave * 16;
    const int lc = lane & 15;
    const int kg = (lane >> 4) * 8;
    const int arow = r0 + lc;

    short8v a[NS];
#pragma unroll
    for (int s = 0; s < NS; ++s) {
        if (arow < N) {
            if (AF32) {
                const float* xp = (const float*)Xv + (size_t)arow * K + s * 32 + kg;
                float4 u = *(const float4*)xp;
                float4 v = *(const float4*)(xp + 4);
                unsigned short e[8] = { f2bf(u.x), f2bf(u.y), f2bf(u.z), f2bf(u.w),
                                        f2bf(v.x), f2bf(v.y), f2bf(v.z), f2bf(v.w) };
                a[s] = *(const short8v*)e;
            } else {
                a[s] = *(const short8v*)((const unsigned short*)Xv
                                         + (size_t)arow * K + s * 32 + kg);
            }
        } else {
            short8v z = { 0, 0, 0, 0, 0, 0, 0, 0 };
            a[s] = z;
        }
    }

#pragma unroll
    for (int ct = 0; ct < NT; ++ct) {
        f32x4 acc = { 0.f, 0.f, 0.f, 0.f };
#pragma unroll
        for (int s = 0; s < NS; ++s) {
            short8v b = *(const short8v*)&Wt[(size_t)(ct * 16 + lc) * K + s * 32 + kg];
            acc = __builtin_amdgcn_mfma_f32_16x16x32_bf16(a[s], b, acc, 0, 0, 0);
        }
#pragma unroll
        for (int i = 0; i < 4; ++i) {
            int gr = r0 + (lane >> 4) * 4 + i;
            if (gr < N) Y[(size_t)gr * C + ct * 16 + lc] = f2bf(acc[i]);
        }
    }
}

// Per-edge H gather: epack.x is the byte offset for C=64 rows; C=32 shifts.
template<int C>
__device__ __forceinline__ float gath(const char* __restrict__ Hb, int ex, int foff) {
    unsigned o = (C == 64) ? (unsigned)ex : ((unsigned)ex >> 1);
    return bf2f(*(const unsigned short*)(Hb + o + foff));
}

// CSR gather aggregation over bf16 H (round-7 8-unrolled loop), fused
// self-loop + bias (+relu). OUT bf16 (intermediate) or f32 (final).
template<int C, bool RELU, bool OBF16>
__global__ __launch_bounds__(256) void agg_kernel(const unsigned short* __restrict__ H,
                                                  const int* __restrict__ rowptr,
                                                  const int2* __restrict__ epack,
                                                  const float* __restrict__ dinv,
                                                  const float* __restrict__ bias,
                                                  void* __restrict__ OUT, int N) {
    constexpr int NPB = 256 / C;
    const int f = threadIdx.x % C;                       // feature lane
    const int node = blockIdx.x * NPB + threadIdx.x / C;
    if (node >= N) return;
    const int lo = rowptr[node], hi = rowptr[node + 1];
    const float di = dinv[node];
    const char* Hb = (const char*)H;
    const int foff = f * 2;

    float a0 = 0.f, a1 = 0.f, a2 = 0.f, a3 = 0.f;
    int i = lo;
    for (; i + 8 <= hi; i += 8) {
        int2 e0 = epack[i + 0], e1 = epack[i + 1], e2 = epack[i + 2], e3 = epack[i + 3];
        int2 e4 = epack[i + 4], e5 = epack[i + 5], e6 = epack[i + 6], e7 = epack[i + 7];
        float h0 = gath<C>(Hb, e0.x, foff);
        float h1 = gath<C>(Hb, e1.x, foff);
        float h2 = gath<C>(Hb, e2.x, foff);
        float h3 = gath<C>(Hb, e3.x, foff);
        float h4 = gath<C>(Hb, e4.x, foff);
        float h5 = gath<C>(Hb, e5.x, foff);
        float h6 = gath<C>(Hb, e6.x, foff);
        float h7 = gath<C>(Hb, e7.x, foff);
        a0 = fmaf(h0, __int_as_float(e0.y), a0);
        a1 = fmaf(h1, __int_as_float(e1.y), a1);
        a2 = fmaf(h2, __int_as_float(e2.y), a2);
        a3 = fmaf(h3, __int_as_float(e3.y), a3);
        a0 = fmaf(h4, __int_as_float(e4.y), a0);
        a1 = fmaf(h5, __int_as_float(e5.y), a1);
        a2 = fmaf(h6, __int_as_float(e6.y), a2);
        a3 = fmaf(h7, __int_as_float(e7.y), a3);
    }
    for (; i + 4 <= hi; i += 4) {
        int2 e0 = epack[i + 0], e1 = epack[i + 1], e2 = epack[i + 2], e3 = epack[i + 3];
        float h0 = gath<C>(Hb, e0.x, foff);
        float h1 = gath<C>(Hb, e1.x, foff);
        float h2 = gath<C>(Hb, e2.x, foff);
        float h3 = gath<C>(Hb, e3.x, foff);
        a0 = fmaf(h0, __int_as_float(e0.y), a0);
        a1 = fmaf(h1, __int_as_float(e1.y), a1);
        a2 = fmaf(h2, __int_as_float(e2.y), a2);
        a3 = fmaf(h3, __int_as_float(e3.y), a3);
    }
    for (; i < hi; ++i) {
        int2 e0 = epack[i];
        a0 = fmaf(gath<C>(Hb, e0.x, foff), __int_as_float(e0.y), a0);
    }

    float r = (a0 + a1) + (a2 + a3)
            + di * di * bf2f(H[(size_t)node * C + f])
            + bias[f];
    if (RELU) r = fmaxf(r, 0.f);
    if (OBF16) ((unsigned short*)OUT)[(size_t)node * C + f] = f2bf(r);
    else       ((float*)OUT)[(size_t)node * C + f] = r;
}

extern "C" void kernel_launch(void* const* d_in, const int* in_sizes, int n_in,
                              void* d_out, int out_size, void* d_ws, size_t ws_size,
                              hipStream_t stream) {
    const float* x  = (const float*)d_in[0];
    const int*   ei = (const int*)d_in[1];
    const float* W1 = (const float*)d_in[2];
    const float* b1 = (const float*)d_in[3];
    const float* W2 = (const float*)d_in[4];
    const float* b2 = (const float*)d_in[5];
    const float* W3 = (const float*)d_in[6];
    const float* b3 = (const float*)d_in[7];
    float* out = (float*)d_out;

    const int N = in_sizes[0] / 128;
    const int E = in_sizes[1] / 2;
    const int* src = ei;
    const int* dst = ei + E;
    const int NSCAN = (N + SCAN_CHUNK - 1) / SCAN_CHUNK;        // 98
    const int NB = (N + BMASK) >> BSHIFT;                        // 391 buckets
    const int NBB = (E + BCH - 1) / BCH;                         // 391 blocks

    auto align = [](size_t v) { return (v + 255) & ~(size_t)255; };
    char* wsb = (char*)d_ws;
    size_t off = 0;
    float* dinv   = (float*)(wsb + off); off += align((size_t)N * 4);
    int*   rowptr = (int*)  (wsb + off); off += align((size_t)(N + 1) * 4);
    int*   degi   = (int*)  (wsb + off); off += align((size_t)N * 4);
    int*   bcur   = (int*)  (wsb + off); off += align((size_t)NB * 4);
    int*   bsum   = (int*)  (wsb + off); off += align((size_t)NSCAN * 4);
    int*   boff   = (int*)  (wsb + off); off += align((size_t)NSCAN * 4);
    unsigned int* bbuf = (unsigned int*)(wsb + off); off += align((size_t)NB * BCAP * 4);
    int2*  epack  = (int2*) (wsb + off); off += align((size_t)E * 8);
    unsigned short* P  = (unsigned short*)(wsb + off); off += align((size_t)N * 64 * 2);
    unsigned short* Q  = (unsigned short*)(wsb + off); off += align((size_t)N * 64 * 2);
    unsigned short* Wt1 = (unsigned short*)(wsb + off); off += align((size_t)8192 * 2);
    unsigned short* Wt2 = (unsigned short*)(wsb + off); off += align((size_t)4096 * 2);
    unsigned short* Wt3 = (unsigned short*)(wsb + off); off += align((size_t)2048 * 2);

    // ---- weight prep + CSR build (no per-edge global atomics) ----
    wcvt_kernel<<<56, 256, 0, stream>>>(W1, W2, W3, Wt1, Wt2, Wt3);
    hipMemsetAsync(bcur, 0, (size_t)NB * 4, stream);
    bucket_kernel<<<NBB, 256, 0, stream>>>(src, dst, bcur, bbuf, E, NB);
    bdeg_kernel<<<NB, 256, 0, stream>>>(bcur, bbuf, degi, dinv, N);
    scanA_kernel<<<NSCAN, 256, 0, stream>>>(degi, bsum, N);
    scanB_kernel<<<1, 256, 0, stream>>>(bsum, boff, rowptr + N, NSCAN);
    scanC_kernel<<<NSCAN, 256, 0, stream>>>(degi, boff, rowptr, N);
    bfill_kernel<<<NB, 256, 0, stream>>>(bcur, bbuf, rowptr, dinv, epack, N);

    const int GB = (N + 63) / 64;   // gemm blocks

    // ---- Layer 1: 128 -> 64, relu ----
    gemm_mfma<128, 64, true><<<GB, 256, 0, stream>>>(x, Wt1, P, N);
    agg_kernel<64, true, true><<<(N * 64 + BLK - 1) / BLK, BLK, 0, stream>>>(
        P, rowptr, epack, dinv, b1, Q, N);

    // ---- Layer 2: 64 -> 64, relu ----
    gemm_mfma<64, 64, false><<<GB, 256, 0, stream>>>(Q, Wt2, P, N);
    agg_kernel<64, true, true><<<(N * 64 + BLK - 1) / BLK, BLK, 0, stream>>>(
        P, rowptr, epack, dinv, b2, Q, N);

    // ---- Layer 3: 64 -> 32, no relu, f32 out ----
    gemm_mfma<64, 32, false><<<GB, 256, 0, stream>>>(Q, Wt3, P, N);
    agg_kernel<32, false, false><<<(N * 32 + BLK - 1) / BLK, BLK, 0, stream>>>(
        P, rowptr, epack, dinv, b3, out, N);
}